// Round 1
// 859.823 us; speedup vs baseline: 1.0191x; 1.0191x over previous
//
#include <hip/hip_runtime.h>
#include <stdint.h>

#define NN 100000
#define NT 500000
#define RP 16
#define RR 16
#define EMB 16
#define NUMCLS 40
#define NRP (NN*RP)          // 1,600,000
#define MM (2*NN)            // concatenated histogram length (by-s | by-o)
#define SCAN_BLOCKS ((MM + 255)/256)   // 782

// ============ CSR build ============
__global__ __launch_bounds__(256) void k_count(const int* __restrict__ s,
                                               const int* __restrict__ o,
                                               int* __restrict__ cnt){
    int t = blockIdx.x*256 + threadIdx.x;
    if (t >= NT) return;
    atomicAdd(&cnt[s[t]], 1);
    atomicAdd(&cnt[NN + o[t]], 1);
}

__global__ __launch_bounds__(256) void k_scan_blk(const int* __restrict__ cnt,
                                                  int* __restrict__ offs,
                                                  int* __restrict__ bsum){
    __shared__ int sm[256];
    int tid = threadIdx.x;
    int i = blockIdx.x*256 + tid;
    int v = (i < MM) ? cnt[i] : 0;
    sm[tid] = v; __syncthreads();
    for (int off = 1; off < 256; off <<= 1){
        int x = (tid >= off) ? sm[tid-off] : 0;
        __syncthreads();
        sm[tid] += x; __syncthreads();
    }
    if (i < MM) offs[i] = sm[tid] - v;       // exclusive within block
    if (tid == 255) bsum[blockIdx.x] = sm[255];
}

__global__ __launch_bounds__(1024) void k_scan_top(const int* __restrict__ bsum,
                                                   int* __restrict__ btot){
    __shared__ int sm[1024];
    int tid = threadIdx.x;
    int v = (tid < SCAN_BLOCKS) ? bsum[tid] : 0;
    sm[tid] = v; __syncthreads();
    for (int off = 1; off < 1024; off <<= 1){
        int x = (tid >= off) ? sm[tid-off] : 0;
        __syncthreads();
        sm[tid] += x; __syncthreads();
    }
    if (tid < SCAN_BLOCKS) btot[tid] = sm[tid] - v;   // exclusive
}

__global__ __launch_bounds__(256) void k_scan_add(int* __restrict__ offs,
                                                  const int* __restrict__ btot,
                                                  int* __restrict__ cur){
    int i = blockIdx.x*256 + threadIdx.x;
    if (i < MM){
        int v = offs[i] + btot[blockIdx.x];
        offs[i] = v;
        cur[i] = v;
    }
    if (i == 0) offs[MM] = 2*NT;
}

__global__ __launch_bounds__(256) void k_fill(const int* __restrict__ s,
                                              const int* __restrict__ o,
                                              int* __restrict__ cur,
                                              int* __restrict__ eb){
    int t = blockIdx.x*256 + threadIdx.x;
    if (t >= NT) return;
    int p = atomicAdd(&cur[s[t]], 1);      eb[p] = t;   // by-s list in [0, NT)
    int q = atomicAdd(&cur[NN + o[t]], 1); eb[q] = t;   // by-o list in [NT, 2NT)
}

// ============ lat1/lat2 softmax (pure streaming, no atomics) ============
__global__ __launch_bounds__(256) void k_lat(
    const float* __restrict__ nhots,
    const float* __restrict__ Wl1, const float* __restrict__ bl1,
    const float* __restrict__ Wl2, const float* __restrict__ bl2,
    float* __restrict__ lat1, float* __restrict__ lat2)
{
    __shared__ float sW1[RP*RR], sW2[RP*RR], sb1[RP], sb2[RP];
    int tid = threadIdx.x;
    if (tid < RP*RR){ sW1[tid] = Wl1[tid]; sW2[tid] = Wl2[tid]; }
    if (tid < RP){ sb1[tid] = bl1[tid]; sb2[tid] = bl2[tid]; }
    __syncthreads();

    int t = blockIdx.x*256 + tid;
    if (t >= NT) return;
    float nh[RR];
    const float4* npx = (const float4*)(nhots + (size_t)t * RR);
    #pragma unroll
    for (int q = 0; q < 4; q++){
        float4 v = npx[q];
        nh[4*q] = v.x; nh[4*q+1] = v.y; nh[4*q+2] = v.z; nh[4*q+3] = v.w;
    }
    float l1[RP], l2[RP];
    #pragma unroll
    for (int r = 0; r < RP; r++){
        float a = sb1[r], b = sb2[r];
        #pragma unroll
        for (int i = 0; i < RR; i++){ a += nh[i]*sW1[r*RR+i]; b += nh[i]*sW2[r*RR+i]; }
        l1[r] = a; l2[r] = b;
    }
    float m1 = l1[0], m2 = l2[0];
    #pragma unroll
    for (int r = 1; r < RP; r++){ m1 = fmaxf(m1, l1[r]); m2 = fmaxf(m2, l2[r]); }
    float s1 = 0.f, s2 = 0.f;
    #pragma unroll
    for (int r = 0; r < RP; r++){
        l1[r] = expf(l1[r]-m1); s1 += l1[r];
        l2[r] = expf(l2[r]-m2); s2 += l2[r];
    }
    float i1 = 1.f/s1, i2 = 1.f/s2;
    float4* o1 = (float4*)(lat1 + (size_t)t*RP);
    float4* o2 = (float4*)(lat2 + (size_t)t*RP);
    #pragma unroll
    for (int q = 0; q < 4; q++){
        o1[q] = make_float4(l1[4*q]*i1, l1[4*q+1]*i1, l1[4*q+2]*i1, l1[4*q+3]*i1);
        o2[q] = make_float4(l2[4*q]*i2, l2[4*q+1]*i2, l2[4*q+2]*i2, l2[4*q+3]*i2);
    }
}

// ============ per-node lat sums + fused r=0 global reductions ============
// Latency fix: chunk-prefetch 16 edge ids with the 16 e-lanes (one coalesced
// eb load), broadcast via __shfl(width=16), then issue all 16 gather loads
// unconditionally (clamped index) so they batch under one memory latency.
__global__ __launch_bounds__(256) void k_CR(const int* __restrict__ offs,
                                            const int* __restrict__ eb,
                                            const float* __restrict__ lat1,
                                            const float* __restrict__ lat2,
                                            float* __restrict__ C,
                                            float* __restrict__ Rm,
                                            float* __restrict__ S0V){
    int gid = blockIdx.x*256 + threadIdx.x;
    int n = gid >> 4, e = gid & 15;
    float accC = 0.f, accR = 0.f;
    if (n < NN){
        int b = offs[NN+n], en = offs[NN+n+1];      // by-o adjacency
        for (int i = b; i < en; i += 16){
            int cnt = en - i;
            int idx = eb[min(i + e, en - 1)];
            #pragma unroll
            for (int j = 0; j < 16; j++){
                int t = __shfl(idx, j, 16);
                float v = lat1[(size_t)t*16 + e];
                accC += (j < cnt) ? v : 0.f;
            }
        }
        C[(size_t)n*16 + e] = accC;
        b = offs[n]; en = offs[n+1];                // by-s adjacency
        for (int i = b; i < en; i += 16){
            int cnt = en - i;
            int idx = eb[min(i + e, en - 1)];
            #pragma unroll
            for (int j = 0; j < 16; j++){
                int t = __shfl(idx, j, 16);
                float v = lat2[(size_t)t*16 + e];
                accR += (j < cnt) ? v : 0.f;
            }
        }
        Rm[(size_t)n*16 + e] = accR;
    }
    __shared__ float sa[16], sb[16];
    int g = threadIdx.x >> 4;
    if (e == 0){ sa[g] = accC; sb[g] = accR; }
    __syncthreads();
    if (threadIdx.x == 0){
        float a = 0.f, b = 0.f;
        #pragma unroll
        for (int k = 0; k < 16; k++){ a += sa[k]; b += sb[k]; }
        unsafeAtomicAdd(&S0V[0], a);
        unsafeAtomicAdd(&S0V[1], b);
    }
}

// ============ divisor sweep: inv colsum/rowsum over flat index c ============
__global__ __launch_bounds__(256) void k_sums(const float* __restrict__ C,
                                              const float* __restrict__ Rm,
                                              const float* __restrict__ S0,
                                              float* __restrict__ invc,
                                              float* __restrict__ invr){
    int c = blockIdx.x*256 + threadIdx.x;
    if (c >= NRP) return;
    float a = 0.f, b = 0.f;
    if (c == 0){ a = S0[0]; b = S0[1]; }
    #pragma unroll
    for (int r = 1; r < RP; r++){
        int q = c / r;                      // const divisor -> magic mul
        if (q*r == c && q < NN){
            a += C[(size_t)q*16 + r];
            b += Rm[(size_t)q*16 + r];
        }
    }
    invc[c] = (a > 0.f) ? 1.f/a : 0.f;
    invr[c] = (b > 0.f) ? 1.f/b : 0.f;
}

// ============ layer-1 phase A (by-o): yt[t][e] = sum_r lat1[t,r]*invc[o*r]*w1[o*r][e] ============
__global__ __launch_bounds__(256) void k_y(const int* __restrict__ offs,
                                           const int* __restrict__ eb,
                                           const float* __restrict__ lat1,
                                           const float* __restrict__ invc,
                                           const float* __restrict__ w1,
                                           float* __restrict__ yt){
    int gid = blockIdx.x*256 + threadIdx.x;
    int o = gid >> 4, e = gid & 15;
    if (o >= NN) return;
    float Wb[RP];                         // thread e holds column e of the 16x16 block
    #pragma unroll
    for (int r = 0; r < RP; r++){
        size_t c = (size_t)o * r;
        Wb[r] = invc[c] * w1[c*16 + e];   // each w1 row read ONCE per node (not per edge)
    }
    int b = offs[NN+o], en = offs[NN+o+1];
    for (int i = b; i < en; i += 16){
        int cnt = en - i;
        int idx = eb[min(i + e, en - 1)];
        #pragma unroll
        for (int j = 0; j < 16; j++){
            int t = __shfl(idx, j, 16);
            const float4* lp = (const float4*)(lat1 + (size_t)t*16);
            float4 v0 = lp[0], v1 = lp[1], v2 = lp[2], v3 = lp[3];
            float y = v0.x*Wb[0] + v0.y*Wb[1] + v0.z*Wb[2] + v0.w*Wb[3]
                    + v1.x*Wb[4] + v1.y*Wb[5] + v1.z*Wb[6] + v1.w*Wb[7]
                    + v2.x*Wb[8] + v2.y*Wb[9] + v2.z*Wb[10]+ v2.w*Wb[11]
                    + v3.x*Wb[12]+ v3.y*Wb[13]+ v3.z*Wb[14]+ v3.w*Wb[15];
            if (j < cnt) yt[(size_t)t*16 + e] = y;
        }
    }
}

// ============ layer-1 phase B (by-s): h[s] = relu(b1 + sum_t yt[t]) ============
__global__ __launch_bounds__(256) void k_h(const int* __restrict__ offs,
                                           const int* __restrict__ eb,
                                           const float* __restrict__ yt,
                                           const float* __restrict__ b1,
                                           float* __restrict__ h){
    int gid = blockIdx.x*256 + threadIdx.x;
    int n = gid >> 4, e = gid & 15;
    if (n >= NN) return;
    int b = offs[n], en = offs[n+1];
    float acc = 0.f;
    for (int i = b; i < en; i += 16){
        int cnt = en - i;
        int idx = eb[min(i + e, en - 1)];
        #pragma unroll
        for (int j = 0; j < 16; j++){
            int t = __shfl(idx, j, 16);
            float v = yt[(size_t)t*16 + e];
            acc += (j < cnt) ? v : 0.f;
        }
    }
    h[(size_t)n*16 + e] = fmaxf(acc + b1[e], 0.f);
}

// ============ P[s][r][e] = sum_{t in adj_s(s)} lat2[t,r]*h[o_t][e]; fused V0h ============
// 3-deep chain (eb -> ocol -> h) collapsed: prefetch idx AND ocol[idx] per-lane
// (parallel across lanes), then batch the h/lat2 gathers in the unrolled loop.
__global__ __launch_bounds__(256) void k_P(const int* __restrict__ offs,
                                           const int* __restrict__ eb,
                                           const int* __restrict__ ocol,
                                           const float* __restrict__ lat2,
                                           const float* __restrict__ h,
                                           float* __restrict__ P,
                                           float* __restrict__ S0V){
    int gid = blockIdx.x*256 + threadIdx.x;
    int n = gid >> 4, e = gid & 15;
    float acc[RP];
    #pragma unroll
    for (int r = 0; r < RP; r++) acc[r] = 0.f;
    if (n < NN){
        int b = offs[n], en = offs[n+1];
        for (int i = b; i < en; i += 16){
            int cnt = en - i;
            int idx = eb[min(i + e, en - 1)];
            int ov  = ocol[idx];
            #pragma unroll
            for (int j = 0; j < 16; j++){
                int t = __shfl(idx, j, 16);
                int o = __shfl(ov,  j, 16);
                float hv = h[(size_t)o*16 + e];
                hv = (j < cnt) ? hv : 0.f;
                const float4* lp = (const float4*)(lat2 + (size_t)t*16);
                float4 v0 = lp[0], v1 = lp[1], v2 = lp[2], v3 = lp[3];
                acc[0] += v0.x*hv; acc[1] += v0.y*hv; acc[2] += v0.z*hv; acc[3] += v0.w*hv;
                acc[4] += v1.x*hv; acc[5] += v1.y*hv; acc[6] += v1.z*hv; acc[7] += v1.w*hv;
                acc[8] += v2.x*hv; acc[9] += v2.y*hv; acc[10]+= v2.z*hv; acc[11]+= v2.w*hv;
                acc[12]+= v3.x*hv; acc[13]+= v3.y*hv; acc[14]+= v3.z*hv; acc[15]+= v3.w*hv;
            }
        }
        float* Pn = P + (size_t)n*256 + e;
        #pragma unroll
        for (int r = 0; r < RP; r++) Pn[r*16] = acc[r];
    }
    // fused: V0h[e] = sum_s P[s][0][e]
    __shared__ float sm[256];
    sm[threadIdx.x] = acc[0]; __syncthreads();
    if (threadIdx.x < 16){
        float s = 0.f;
        #pragma unroll
        for (int k = 0; k < 16; k++) s += sm[k*16 + threadIdx.x];
        unsafeAtomicAdd(&S0V[2 + threadIdx.x], s);
    }
}

// ============ fused h2 + output einsum ============
__global__ __launch_bounds__(256) void k_out(const float* __restrict__ P,
                                             const float* __restrict__ invr,
                                             const float* __restrict__ S0V,
                                             const float* __restrict__ w2,
                                             const float* __restrict__ b2,
                                             float* __restrict__ out){
    int n = blockIdx.x*256 + threadIdx.x;
    if (n >= NN) return;
    float acc[NUMCLS];
    #pragma unroll
    for (int cl = 0; cl < NUMCLS; cl++) acc[cl] = b2[cl];
    #pragma unroll 1
    for (int rr = 0; rr < RP; rr++){
        int c = rr*NN + n;                 // flat h2 row consumed exactly once
        float hrow[EMB];
        #pragma unroll
        for (int e = 0; e < EMB; e++) hrow[e] = 0.f;
        if (c == 0){
            #pragma unroll
            for (int e = 0; e < EMB; e++) hrow[e] = S0V[2 + e];
        }
        #pragma unroll
        for (int r = 1; r < RP; r++){
            int q = c / r;                 // const divisor -> magic mul
            if (q*r == c && q < NN){
                const float* Pr = P + (size_t)q*256 + r*16;
                #pragma unroll
                for (int e = 0; e < EMB; e++) hrow[e] += Pr[e];
            }
        }
        float inv = invr[c];
        const float* wr = w2 + (size_t)rr*EMB*NUMCLS;   // wave-uniform -> s_load
        #pragma unroll
        for (int e = 0; e < EMB; e++){
            float x = hrow[e] * inv;
            #pragma unroll
            for (int cl = 0; cl < NUMCLS; cl++) acc[cl] += x * wr[e*NUMCLS + cl];
        }
    }
    float4* op = (float4*)(out + (size_t)n*NUMCLS);
    #pragma unroll
    for (int q = 0; q < NUMCLS/4; q++)
        op[q] = make_float4(acc[4*q], acc[4*q+1], acc[4*q+2], acc[4*q+3]);
}

extern "C" void kernel_launch(void* const* d_in, const int* in_sizes, int n_in,
                              void* d_out, int out_size, void* d_ws, size_t ws_size,
                              hipStream_t stream)
{
    const float* nhots = (const float*)d_in[0];
    const float* Wl1   = (const float*)d_in[1];
    const float* bl1   = (const float*)d_in[2];
    const float* Wl2   = (const float*)d_in[3];
    const float* bl2   = (const float*)d_in[4];
    const float* w1    = (const float*)d_in[5];
    const float* w2    = (const float*)d_in[6];
    const float* b1    = (const float*)d_in[7];
    const float* b2    = (const float*)d_in[8];
    const int* srow = (const int*)d_in[9];    // hrow[t] = s[t] for t < NT
    const int* ocol = (const int*)d_in[12];   // vcol[t] = o[t] for t < NT

    // ---- workspace layout (floats) ----
    float* base = (float*)d_ws;
    float* P    = base;                         // 25.6M floats (NN*256)
    float* lat1 = base;                         // 8M
    float* C    = base + (size_t)8000000;       // 1.6M
    float* Rm   = base + (size_t)9600000;       // 1.6M
    float* yt   = base + (size_t)8000000;       // 8M  (aliases C/Rm after k_sums)
    float* lat2 = base + (size_t)25600000;      // 8M
    float* invc = base + (size_t)33600000;      // 1.6M
    float* invr = base + (size_t)35200000;      // 1.6M
    float* h    = base + (size_t)36800000;      // 1.6M
    float* S0V  = base + (size_t)38400000;      // 32: [S0c, S0r, V0h[16], pad]
    int*   cnt  = (int*)(base + (size_t)38400032);
    int*   offs = cnt + MM;                     // MM+1
    int*   cur  = offs + (MM+1);
    int*   bsum = cur + MM;                     // SCAN_BLOCKS (pad to 1024)
    int*   btot = bsum + 1024;
    int*   eb   = btot + 1024;                  // 2*NT = 1M
    // total ~160 MB

    hipMemsetAsync(cnt, 0, (size_t)MM*4, stream);
    hipMemsetAsync(S0V, 0, 32*4, stream);

    const int EB = (NT + 255)/256;       // 1954
    const int NB16 = (NN*16 + 255)/256;  // 6250
    const int CB = (NRP + 255)/256;      // 6250
    const int NB = (NN + 255)/256;       // 391

    k_count   <<<EB, 256, 0, stream>>>(srow, ocol, cnt);
    k_scan_blk<<<SCAN_BLOCKS, 256, 0, stream>>>(cnt, offs, bsum);
    k_scan_top<<<1, 1024, 0, stream>>>(bsum, btot);
    k_scan_add<<<SCAN_BLOCKS, 256, 0, stream>>>(offs, btot, cur);
    k_fill    <<<EB, 256, 0, stream>>>(srow, ocol, cur, eb);
    k_lat     <<<EB, 256, 0, stream>>>(nhots, Wl1, bl1, Wl2, bl2, lat1, lat2);
    k_CR      <<<NB16, 256, 0, stream>>>(offs, eb, lat1, lat2, C, Rm, S0V);
    k_sums    <<<CB, 256, 0, stream>>>(C, Rm, S0V, invc, invr);
    k_y       <<<NB16, 256, 0, stream>>>(offs, eb, lat1, invc, w1, yt);
    k_h       <<<NB16, 256, 0, stream>>>(offs, eb, yt, b1, h);
    k_P       <<<NB16, 256, 0, stream>>>(offs, eb, ocol, lat2, h, P, S0V);
    k_out     <<<NB, 256, 0, stream>>>(P, invr, S0V, w2, b2, (float*)d_out);
}

// Round 2
// 807.971 us; speedup vs baseline: 1.0845x; 1.0642x over previous
//
#include <hip/hip_runtime.h>
#include <stdint.h>

#define NN 100000
#define NT 500000
#define RP 16
#define RR 16
#define EMB 16
#define NUMCLS 40
#define NRP (NN*RP)          // 1,600,000
#define MM (2*NN)            // concatenated histogram length (by-s | by-o)
#define SCAN_BLOCKS ((MM + 255)/256)   // 782

// ============ CSR build ============
__global__ __launch_bounds__(256) void k_count(const int* __restrict__ s,
                                               const int* __restrict__ o,
                                               int* __restrict__ cnt){
    int t = blockIdx.x*256 + threadIdx.x;
    if (t >= NT) return;
    atomicAdd(&cnt[s[t]], 1);
    atomicAdd(&cnt[NN + o[t]], 1);
}

__global__ __launch_bounds__(256) void k_scan_blk(const int* __restrict__ cnt,
                                                  int* __restrict__ offs,
                                                  int* __restrict__ bsum){
    __shared__ int sm[256];
    int tid = threadIdx.x;
    int i = blockIdx.x*256 + tid;
    int v = (i < MM) ? cnt[i] : 0;
    sm[tid] = v; __syncthreads();
    for (int off = 1; off < 256; off <<= 1){
        int x = (tid >= off) ? sm[tid-off] : 0;
        __syncthreads();
        sm[tid] += x; __syncthreads();
    }
    if (i < MM) offs[i] = sm[tid] - v;       // exclusive within block
    if (tid == 255) bsum[blockIdx.x] = sm[255];
}

__global__ __launch_bounds__(1024) void k_scan_top(const int* __restrict__ bsum,
                                                   int* __restrict__ btot){
    __shared__ int sm[1024];
    int tid = threadIdx.x;
    int v = (tid < SCAN_BLOCKS) ? bsum[tid] : 0;
    sm[tid] = v; __syncthreads();
    for (int off = 1; off < 1024; off <<= 1){
        int x = (tid >= off) ? sm[tid-off] : 0;
        __syncthreads();
        sm[tid] += x; __syncthreads();
    }
    if (tid < SCAN_BLOCKS) btot[tid] = sm[tid] - v;   // exclusive
}

__global__ __launch_bounds__(256) void k_scan_add(int* __restrict__ offs,
                                                  const int* __restrict__ btot,
                                                  int* __restrict__ cur){
    int i = blockIdx.x*256 + threadIdx.x;
    if (i < MM){
        int v = offs[i] + btot[blockIdx.x];
        offs[i] = v;
        cur[i] = v;
    }
    if (i == 0) offs[MM] = 2*NT;
}

// ============ fused slot-claim + softmax + CSR-ordered scatter ============
// Each edge claims its by-s slot p (in [0,NT)) and by-o slot q (in [NT,2NT),
// stored rebased to [0,NT)), computes both softmaxes, then the block
// cooperatively scatter-writes 64B rows: lat1q (by-o order), lat2p (by-s
// order). All later kernels read these SEQUENTIALLY.
__global__ __launch_bounds__(256) void k_lat(
    const float* __restrict__ nhots,
    const float* __restrict__ Wl1, const float* __restrict__ bl1,
    const float* __restrict__ Wl2, const float* __restrict__ bl2,
    const int* __restrict__ srow, const int* __restrict__ ocol,
    int* __restrict__ cur,
    float* __restrict__ lat1q, float* __restrict__ lat2p,
    int* __restrict__ o_at_p, int* __restrict__ s_at_q)
{
    __shared__ float sW1[RP*RR], sW2[RP*RR], sb1[RP], sb2[RP];
    __shared__ float st1[256][17], st2[256][17];   // +1 pad: kills 32-way write conflict
    __shared__ int sq[256], sp[256];
    int tid = threadIdx.x;
    if (tid < RP*RR){ sW1[tid] = Wl1[tid]; sW2[tid] = Wl2[tid]; }
    if (tid < RP){ sb1[tid] = bl1[tid]; sb2[tid] = bl2[tid]; }
    __syncthreads();

    int t = blockIdx.x*256 + tid;
    int p = -1, q = -1;
    if (t < NT){
        int s_ = srow[t], o_ = ocol[t];
        p = atomicAdd(&cur[s_], 1);             // by-s slot in [0, NT)
        q = atomicAdd(&cur[NN + o_], 1) - NT;   // by-o slot rebased to [0, NT)
        o_at_p[p] = o_;                         // 4B scatter into 2MB (L2-absorbed)
        s_at_q[q] = s_;

        float nh[RR];
        const float4* npx = (const float4*)(nhots + (size_t)t * RR);
        #pragma unroll
        for (int u = 0; u < 4; u++){
            float4 v = npx[u];
            nh[4*u] = v.x; nh[4*u+1] = v.y; nh[4*u+2] = v.z; nh[4*u+3] = v.w;
        }
        float l1[RP], l2[RP];
        #pragma unroll
        for (int r = 0; r < RP; r++){
            float a = sb1[r], b = sb2[r];
            #pragma unroll
            for (int i = 0; i < RR; i++){ a += nh[i]*sW1[r*RR+i]; b += nh[i]*sW2[r*RR+i]; }
            l1[r] = a; l2[r] = b;
        }
        float m1 = l1[0], m2 = l2[0];
        #pragma unroll
        for (int r = 1; r < RP; r++){ m1 = fmaxf(m1, l1[r]); m2 = fmaxf(m2, l2[r]); }
        float s1 = 0.f, s2 = 0.f;
        #pragma unroll
        for (int r = 0; r < RP; r++){
            l1[r] = expf(l1[r]-m1); s1 += l1[r];
            l2[r] = expf(l2[r]-m2); s2 += l2[r];
        }
        float i1 = 1.f/s1, i2 = 1.f/s2;
        #pragma unroll
        for (int r = 0; r < RP; r++){ st1[tid][r] = l1[r]*i1; st2[tid][r] = l2[r]*i2; }
    }
    sq[tid] = q; sp[tid] = p;
    __syncthreads();

    // cooperative scatter: 16 groups of 16 lanes; each group writes one 64B row
    int g = tid >> 4, e = tid & 15;
    #pragma unroll
    for (int k = 0; k < 16; k++){
        int ei = k*16 + g;
        int qq = sq[ei];
        if (qq >= 0){
            lat1q[(size_t)qq*16 + e] = st1[ei][e];
            lat2p[(size_t)sp[ei]*16 + e] = st2[ei][e];
        }
    }
}

// ============ per-node lat sums — now pure sequential streams ============
__global__ __launch_bounds__(256) void k_CR(const int* __restrict__ offs,
                                            const float* __restrict__ lat1q,
                                            const float* __restrict__ lat2p,
                                            float* __restrict__ C,
                                            float* __restrict__ Rm,
                                            float* __restrict__ S0V){
    int gid = blockIdx.x*256 + threadIdx.x;
    int n = gid >> 4, e = gid & 15;
    float accC = 0.f, accR = 0.f;
    if (n < NN){
        int b = offs[NN+n] - NT, en = offs[NN+n+1] - NT;   // by-o range (rebased)
        for (int i = b; i < en; i++) accC += lat1q[(size_t)i*16 + e];
        C[(size_t)n*16 + e] = accC;
        b = offs[n]; en = offs[n+1];                        // by-s range
        for (int i = b; i < en; i++) accR += lat2p[(size_t)i*16 + e];
        Rm[(size_t)n*16 + e] = accR;
    }
    __shared__ float sa[16], sb[16];
    int g = threadIdx.x >> 4;
    if (e == 0){ sa[g] = accC; sb[g] = accR; }
    __syncthreads();
    if (threadIdx.x == 0){
        float a = 0.f, b = 0.f;
        #pragma unroll
        for (int k = 0; k < 16; k++){ a += sa[k]; b += sb[k]; }
        unsafeAtomicAdd(&S0V[0], a);
        unsafeAtomicAdd(&S0V[1], b);
    }
}

// ============ divisor sweep: inv colsum/rowsum over flat index c ============
__global__ __launch_bounds__(256) void k_sums(const float* __restrict__ C,
                                              const float* __restrict__ Rm,
                                              const float* __restrict__ S0,
                                              float* __restrict__ invc,
                                              float* __restrict__ invr){
    int c = blockIdx.x*256 + threadIdx.x;
    if (c >= NRP) return;
    float a = 0.f, b = 0.f;
    if (c == 0){ a = S0[0]; b = S0[1]; }
    #pragma unroll
    for (int r = 1; r < RP; r++){
        int q = c / r;                      // const divisor -> magic mul
        if (q*r == c && q < NN){
            a += C[(size_t)q*16 + r];
            b += Rm[(size_t)q*16 + r];
        }
    }
    invc[c] = (a > 0.f) ? 1.f/a : 0.f;
    invr[c] = (b > 0.f) ? 1.f/b : 0.f;
}

// ============ layer 1: per-o edge y = lat1row . Wb, scatter-add into hsum ============
// lat1q rows are sequential; the only scatter is a fire-and-forget f32 atomic
// into the 6.4MB hsum region (L2-friendly). Replaces old k_y + k_h + 64MB yt.
__global__ __launch_bounds__(256) void k_y(const int* __restrict__ offs,
                                           const float* __restrict__ lat1q,
                                           const int* __restrict__ s_at_q,
                                           const float* __restrict__ invc,
                                           const float* __restrict__ w1,
                                           float* __restrict__ hsum){
    int gid = blockIdx.x*256 + threadIdx.x;
    int o = gid >> 4, e = gid & 15;
    if (o >= NN) return;
    float Wb[RP];                         // thread e holds column e of the 16x16 block
    #pragma unroll
    for (int r = 0; r < RP; r++){
        size_t c = (size_t)o * r;
        Wb[r] = invc[c] * w1[c*16 + e];   // each w1 row read ONCE per node
    }
    int b = offs[NN+o] - NT, en = offs[NN+o+1] - NT;
    for (int i = b; i < en; i++){
        const float4* lp = (const float4*)(lat1q + (size_t)i*16);  // broadcast read
        float4 v0 = lp[0], v1 = lp[1], v2 = lp[2], v3 = lp[3];
        float y = v0.x*Wb[0] + v0.y*Wb[1] + v0.z*Wb[2] + v0.w*Wb[3]
                + v1.x*Wb[4] + v1.y*Wb[5] + v1.z*Wb[6] + v1.w*Wb[7]
                + v2.x*Wb[8] + v2.y*Wb[9] + v2.z*Wb[10]+ v2.w*Wb[11]
                + v3.x*Wb[12]+ v3.y*Wb[13]+ v3.z*Wb[14]+ v3.w*Wb[15];
        int s = s_at_q[i];
        unsafeAtomicAdd(&hsum[(size_t)s*16 + e], y);
    }
}

// ============ P[s][r][e] = sum lat2row[r]*relu(hsum[o]+b1); fused V0h ============
// lat2p + o_at_p sequential; hsum gather is into a 6.4MB L2/L3-resident region.
// bias+relu folded into the gather (h never materialized). P stores r=1..15 only.
__global__ __launch_bounds__(256) void k_P(const int* __restrict__ offs,
                                           const int* __restrict__ o_at_p,
                                           const float* __restrict__ lat2p,
                                           const float* __restrict__ hsum,
                                           const float* __restrict__ b1,
                                           float* __restrict__ P,
                                           float* __restrict__ S0V){
    int gid = blockIdx.x*256 + threadIdx.x;
    int n = gid >> 4, e = gid & 15;
    float be = b1[e];
    float acc[RP];
    #pragma unroll
    for (int r = 0; r < RP; r++) acc[r] = 0.f;
    if (n < NN){
        int b = offs[n], en = offs[n+1];
        for (int i = b; i < en; i++){
            int o = o_at_p[i];
            float hv = fmaxf(hsum[(size_t)o*16 + e] + be, 0.f);
            const float4* lp = (const float4*)(lat2p + (size_t)i*16);
            float4 v0 = lp[0], v1 = lp[1], v2 = lp[2], v3 = lp[3];
            acc[0] += v0.x*hv; acc[1] += v0.y*hv; acc[2] += v0.z*hv; acc[3] += v0.w*hv;
            acc[4] += v1.x*hv; acc[5] += v1.y*hv; acc[6] += v1.z*hv; acc[7] += v1.w*hv;
            acc[8] += v2.x*hv; acc[9] += v2.y*hv; acc[10]+= v2.z*hv; acc[11]+= v2.w*hv;
            acc[12]+= v3.x*hv; acc[13]+= v3.y*hv; acc[14]+= v3.z*hv; acc[15]+= v3.w*hv;
        }
        float* Pn = P + (size_t)n*240 + e;      // rows r=1..15 only
        #pragma unroll
        for (int r = 1; r < RP; r++) Pn[(r-1)*16] = acc[r];
    }
    // fused: V0h[e] = sum_s acc[0]
    __shared__ float sm[256];
    sm[threadIdx.x] = acc[0]; __syncthreads();
    if (threadIdx.x < 16){
        float s = 0.f;
        #pragma unroll
        for (int k = 0; k < 16; k++) s += sm[k*16 + threadIdx.x];
        unsafeAtomicAdd(&S0V[2 + threadIdx.x], s);
    }
}

// ============ fused h2 + output einsum ============
__global__ __launch_bounds__(256) void k_out(const float* __restrict__ P,
                                             const float* __restrict__ invr,
                                             const float* __restrict__ S0V,
                                             const float* __restrict__ w2,
                                             const float* __restrict__ b2,
                                             float* __restrict__ out){
    int n = blockIdx.x*256 + threadIdx.x;
    if (n >= NN) return;
    float acc[NUMCLS];
    #pragma unroll
    for (int cl = 0; cl < NUMCLS; cl++) acc[cl] = b2[cl];
    #pragma unroll 1
    for (int rr = 0; rr < RP; rr++){
        int c = rr*NN + n;                 // flat h2 row consumed exactly once
        float hrow[EMB];
        #pragma unroll
        for (int e = 0; e < EMB; e++) hrow[e] = 0.f;
        if (c == 0){
            #pragma unroll
            for (int e = 0; e < EMB; e++) hrow[e] = S0V[2 + e];
        }
        #pragma unroll
        for (int r = 1; r < RP; r++){
            int q = c / r;                 // const divisor -> magic mul
            if (q*r == c && q < NN){
                const float* Pr = P + (size_t)q*240 + (r-1)*16;
                #pragma unroll
                for (int e = 0; e < EMB; e++) hrow[e] += Pr[e];
            }
        }
        float inv = invr[c];
        const float* wr = w2 + (size_t)rr*EMB*NUMCLS;   // wave-uniform -> s_load
        #pragma unroll
        for (int e = 0; e < EMB; e++){
            float x = hrow[e] * inv;
            #pragma unroll
            for (int cl = 0; cl < NUMCLS; cl++) acc[cl] += x * wr[e*NUMCLS + cl];
        }
    }
    float4* op = (float4*)(out + (size_t)n*NUMCLS);
    #pragma unroll
    for (int q = 0; q < NUMCLS/4; q++)
        op[q] = make_float4(acc[4*q], acc[4*q+1], acc[4*q+2], acc[4*q+3]);
}

extern "C" void kernel_launch(void* const* d_in, const int* in_sizes, int n_in,
                              void* d_out, int out_size, void* d_ws, size_t ws_size,
                              hipStream_t stream)
{
    const float* nhots = (const float*)d_in[0];
    const float* Wl1   = (const float*)d_in[1];
    const float* bl1   = (const float*)d_in[2];
    const float* Wl2   = (const float*)d_in[3];
    const float* bl2   = (const float*)d_in[4];
    const float* w1    = (const float*)d_in[5];
    const float* w2    = (const float*)d_in[6];
    const float* b1    = (const float*)d_in[7];
    const float* b2    = (const float*)d_in[8];
    const int* srow = (const int*)d_in[9];    // hrow[t] = s[t] for t < NT
    const int* ocol = (const int*)d_in[12];   // vcol[t] = o[t] for t < NT

    // ---- workspace layout (floats) ----
    // Lifetimes: lat1q live k_lat->k_y; C/Rm live k_CR->k_sums; P written in
    // k_P (after all three dead) -> all alias inside P's 24M-float region.
    float* base = (float*)d_ws;
    float* P     = base;                        // 24M floats (NN*240)
    float* lat1q = base;                        // 8M  (dead after k_y)
    float* C     = base + (size_t)8000000;      // 1.6M (dead after k_sums)
    float* Rm    = base + (size_t)9600000;      // 1.6M (dead after k_sums)
    float* lat2p = base + (size_t)24000000;     // 8M  (live k_lat -> k_P)
    float* invc  = base + (size_t)32000000;     // 1.6M
    float* invr  = base + (size_t)33600000;     // 1.6M
    float* hsum  = base + (size_t)35200000;     // 1.6M
    float* S0V   = base + (size_t)36800000;     // 32: [S0c, S0r, V0h[16], pad]
    int*   cnt   = (int*)(base + (size_t)36800032);
    int*   cur   = cnt;                         // cnt dead after scan -> reuse as cur
    int*   offs  = cnt + MM;                    // MM+1
    int*   bsum  = offs + (MM+1);               // SCAN_BLOCKS (pad to 1024)
    int*   btot  = bsum + 1024;
    int*   o_at_p = btot + 1024;                // NT
    int*   s_at_q = o_at_p + NT;                // NT
    // total ~153 MB (under previous 160 MB footprint)

    hipMemsetAsync(cnt, 0, (size_t)MM*4, stream);
    hipMemsetAsync(S0V, 0, 32*4, stream);
    hipMemsetAsync(hsum, 0, (size_t)NN*16*4, stream);

    const int EB = (NT + 255)/256;       // 1954
    const int NB16 = (NN*16 + 255)/256;  // 6250
    const int CB = (NRP + 255)/256;      // 6250
    const int NB = (NN + 255)/256;       // 391

    k_count   <<<EB, 256, 0, stream>>>(srow, ocol, cnt);
    k_scan_blk<<<SCAN_BLOCKS, 256, 0, stream>>>(cnt, offs, bsum);
    k_scan_top<<<1, 1024, 0, stream>>>(bsum, btot);
    k_scan_add<<<SCAN_BLOCKS, 256, 0, stream>>>(offs, btot, cur);
    k_lat     <<<EB, 256, 0, stream>>>(nhots, Wl1, bl1, Wl2, bl2, srow, ocol,
                                       cur, lat1q, lat2p, o_at_p, s_at_q);
    k_CR      <<<NB16, 256, 0, stream>>>(offs, lat1q, lat2p, C, Rm, S0V);
    k_sums    <<<CB, 256, 0, stream>>>(C, Rm, S0V, invc, invr);
    k_y       <<<NB16, 256, 0, stream>>>(offs, lat1q, s_at_q, invc, w1, hsum);
    k_P       <<<NB16, 256, 0, stream>>>(offs, o_at_p, lat2p, hsum, b1, P, S0V);
    k_out     <<<NB, 256, 0, stream>>>(P, invr, S0V, w2, b2, (float*)d_out);
}

// Round 3
// 628.707 us; speedup vs baseline: 1.3938x; 1.2851x over previous
//
#include <hip/hip_runtime.h>
#include <stdint.h>

#define NN 100000
#define NT 500000
#define RP 16
#define RR 16
#define EMB 16
#define NUMCLS 40
#define NRP (NN*RP)          // 1,600,000
#define MM (2*NN)            // concatenated histogram length (by-s | by-o)
#define SCAN_BLOCKS ((MM + 255)/256)   // 782
#define NB16 6250            // (NN*16 + 255)/256

// ============ CSR build ============
__global__ __launch_bounds__(256) void k_count(const int* __restrict__ s,
                                               const int* __restrict__ o,
                                               int* __restrict__ cnt){
    int t = blockIdx.x*256 + threadIdx.x;
    if (t >= NT) return;
    atomicAdd(&cnt[s[t]], 1);
    atomicAdd(&cnt[NN + o[t]], 1);
}

__global__ __launch_bounds__(256) void k_scan_blk(const int* __restrict__ cnt,
                                                  int* __restrict__ offs,
                                                  int* __restrict__ bsum){
    __shared__ int sm[256];
    int tid = threadIdx.x;
    int i = blockIdx.x*256 + tid;
    int v = (i < MM) ? cnt[i] : 0;
    sm[tid] = v; __syncthreads();
    for (int off = 1; off < 256; off <<= 1){
        int x = (tid >= off) ? sm[tid-off] : 0;
        __syncthreads();
        sm[tid] += x; __syncthreads();
    }
    if (i < MM) offs[i] = sm[tid] - v;       // exclusive within block
    if (tid == 255) bsum[blockIdx.x] = sm[255];
}

__global__ __launch_bounds__(1024) void k_scan_top(const int* __restrict__ bsum,
                                                   int* __restrict__ btot){
    __shared__ int sm[1024];
    int tid = threadIdx.x;
    int v = (tid < SCAN_BLOCKS) ? bsum[tid] : 0;
    sm[tid] = v; __syncthreads();
    for (int off = 1; off < 1024; off <<= 1){
        int x = (tid >= off) ? sm[tid-off] : 0;
        __syncthreads();
        sm[tid] += x; __syncthreads();
    }
    if (tid < SCAN_BLOCKS) btot[tid] = sm[tid] - v;   // exclusive
}

__global__ __launch_bounds__(256) void k_scan_add(int* __restrict__ offs,
                                                  const int* __restrict__ btot,
                                                  int* __restrict__ cur){
    int i = blockIdx.x*256 + threadIdx.x;
    if (i < MM){
        int v = offs[i] + btot[blockIdx.x];
        offs[i] = v;
        cur[i] = v;
    }
    if (i == 0) offs[MM] = 2*NT;
}

// ============ fused slot-claim + softmax + CSR-ordered scatter ============
__global__ __launch_bounds__(256) void k_lat(
    const float* __restrict__ nhots,
    const float* __restrict__ Wl1, const float* __restrict__ bl1,
    const float* __restrict__ Wl2, const float* __restrict__ bl2,
    const int* __restrict__ srow, const int* __restrict__ ocol,
    int* __restrict__ cur,
    float* __restrict__ lat1q, float* __restrict__ lat2p,
    int* __restrict__ o_at_p, int* __restrict__ s_at_q)
{
    __shared__ float sW1[RP*RR], sW2[RP*RR], sb1[RP], sb2[RP];
    __shared__ float st1[256][17], st2[256][17];   // +1 pad: kills 32-way write conflict
    __shared__ int sq[256], sp[256];
    int tid = threadIdx.x;
    if (tid < RP*RR){ sW1[tid] = Wl1[tid]; sW2[tid] = Wl2[tid]; }
    if (tid < RP){ sb1[tid] = bl1[tid]; sb2[tid] = bl2[tid]; }
    __syncthreads();

    int t = blockIdx.x*256 + tid;
    int p = -1, q = -1;
    if (t < NT){
        int s_ = srow[t], o_ = ocol[t];
        p = atomicAdd(&cur[s_], 1);             // by-s slot in [0, NT)
        q = atomicAdd(&cur[NN + o_], 1) - NT;   // by-o slot rebased to [0, NT)
        o_at_p[p] = o_;                         // 4B scatter into 2MB (L2-absorbed)
        s_at_q[q] = s_;

        float nh[RR];
        const float4* npx = (const float4*)(nhots + (size_t)t * RR);
        #pragma unroll
        for (int u = 0; u < 4; u++){
            float4 v = npx[u];
            nh[4*u] = v.x; nh[4*u+1] = v.y; nh[4*u+2] = v.z; nh[4*u+3] = v.w;
        }
        float l1[RP], l2[RP];
        #pragma unroll
        for (int r = 0; r < RP; r++){
            float a = sb1[r], b = sb2[r];
            #pragma unroll
            for (int i = 0; i < RR; i++){ a += nh[i]*sW1[r*RR+i]; b += nh[i]*sW2[r*RR+i]; }
            l1[r] = a; l2[r] = b;
        }
        float m1 = l1[0], m2 = l2[0];
        #pragma unroll
        for (int r = 1; r < RP; r++){ m1 = fmaxf(m1, l1[r]); m2 = fmaxf(m2, l2[r]); }
        float s1 = 0.f, s2 = 0.f;
        #pragma unroll
        for (int r = 0; r < RP; r++){
            l1[r] = expf(l1[r]-m1); s1 += l1[r];
            l2[r] = expf(l2[r]-m2); s2 += l2[r];
        }
        float i1 = 1.f/s1, i2 = 1.f/s2;
        #pragma unroll
        for (int r = 0; r < RP; r++){ st1[tid][r] = l1[r]*i1; st2[tid][r] = l2[r]*i2; }
    }
    sq[tid] = q; sp[tid] = p;
    __syncthreads();

    // cooperative scatter: 16 groups of 16 lanes; each group writes one 64B row
    int g = tid >> 4, e = tid & 15;
    #pragma unroll
    for (int k = 0; k < 16; k++){
        int ei = k*16 + g;
        int qq = sq[ei];
        if (qq >= 0){
            lat1q[(size_t)qq*16 + e] = st1[ei][e];
            lat2p[(size_t)sp[ei]*16 + e] = st2[ei][e];
        }
    }
}

// ============ per-node lat sums — sequential streams, per-block partials ============
__global__ __launch_bounds__(256) void k_CR(const int* __restrict__ offs,
                                            const float* __restrict__ lat1q,
                                            const float* __restrict__ lat2p,
                                            float* __restrict__ C,
                                            float* __restrict__ Rm,
                                            float* __restrict__ pbC,
                                            float* __restrict__ pbR){
    int gid = blockIdx.x*256 + threadIdx.x;
    int n = gid >> 4, e = gid & 15;
    float accC = 0.f, accR = 0.f;
    if (n < NN){
        int b = offs[NN+n] - NT, en = offs[NN+n+1] - NT;   // by-o range (rebased)
        for (int i = b; i < en; i++) accC += lat1q[(size_t)i*16 + e];
        C[(size_t)n*16 + e] = accC;
        b = offs[n]; en = offs[n+1];                        // by-s range
        for (int i = b; i < en; i++) accR += lat2p[(size_t)i*16 + e];
        Rm[(size_t)n*16 + e] = accR;
    }
    // per-block partials (NO same-address atomics — that was the 167us floor)
    __shared__ float sa[16], sb[16];
    int g = threadIdx.x >> 4;
    if (e == 0){ sa[g] = accC; sb[g] = accR; }
    __syncthreads();
    if (threadIdx.x == 0){
        float a = 0.f, b = 0.f;
        #pragma unroll
        for (int k = 0; k < 16; k++){ a += sa[k]; b += sb[k]; }
        pbC[blockIdx.x] = a;
        pbR[blockIdx.x] = b;
    }
}

// ============ reduce per-block partials -> S0V[0], S0V[1] ============
__global__ __launch_bounds__(1024) void k_red1(const float* __restrict__ pbC,
                                               const float* __restrict__ pbR,
                                               float* __restrict__ S0V){
    __shared__ float sa[1024], sb[1024];
    int tid = threadIdx.x;
    float a = 0.f, b = 0.f;
    for (int i = tid; i < NB16; i += 1024){ a += pbC[i]; b += pbR[i]; }
    sa[tid] = a; sb[tid] = b; __syncthreads();
    for (int off = 512; off > 0; off >>= 1){
        if (tid < off){ sa[tid] += sa[tid+off]; sb[tid] += sb[tid+off]; }
        __syncthreads();
    }
    if (tid == 0){ S0V[0] = sa[0]; S0V[1] = sb[0]; }
}

// ============ divisor sweep: inv colsum/rowsum over flat index c ============
__global__ __launch_bounds__(256) void k_sums(const float* __restrict__ C,
                                              const float* __restrict__ Rm,
                                              const float* __restrict__ S0,
                                              float* __restrict__ invc,
                                              float* __restrict__ invr){
    int c = blockIdx.x*256 + threadIdx.x;
    if (c >= NRP) return;
    float a = 0.f, b = 0.f;
    if (c == 0){ a = S0[0]; b = S0[1]; }
    #pragma unroll
    for (int r = 1; r < RP; r++){
        int q = c / r;                      // const divisor -> magic mul
        if (q*r == c && q < NN){
            a += C[(size_t)q*16 + r];
            b += Rm[(size_t)q*16 + r];
        }
    }
    invc[c] = (a > 0.f) ? 1.f/a : 0.f;
    invr[c] = (b > 0.f) ? 1.f/b : 0.f;
}

// ============ layer 1: per-o edge y = lat1row . Wb, scatter-add into hsum ============
__global__ __launch_bounds__(256) void k_y(const int* __restrict__ offs,
                                           const float* __restrict__ lat1q,
                                           const int* __restrict__ s_at_q,
                                           const float* __restrict__ invc,
                                           const float* __restrict__ w1,
                                           float* __restrict__ hsum){
    int gid = blockIdx.x*256 + threadIdx.x;
    int o = gid >> 4, e = gid & 15;
    if (o >= NN) return;
    float Wb[RP];                         // thread e holds column e of the 16x16 block
    #pragma unroll
    for (int r = 0; r < RP; r++){
        size_t c = (size_t)o * r;
        Wb[r] = invc[c] * w1[c*16 + e];   // each w1 row read ONCE per node
    }
    int b = offs[NN+o] - NT, en = offs[NN+o+1] - NT;
    for (int i = b; i < en; i++){
        const float4* lp = (const float4*)(lat1q + (size_t)i*16);  // broadcast read
        float4 v0 = lp[0], v1 = lp[1], v2 = lp[2], v3 = lp[3];
        float y = v0.x*Wb[0] + v0.y*Wb[1] + v0.z*Wb[2] + v0.w*Wb[3]
                + v1.x*Wb[4] + v1.y*Wb[5] + v1.z*Wb[6] + v1.w*Wb[7]
                + v2.x*Wb[8] + v2.y*Wb[9] + v2.z*Wb[10]+ v2.w*Wb[11]
                + v3.x*Wb[12]+ v3.y*Wb[13]+ v3.z*Wb[14]+ v3.w*Wb[15];
        int s = s_at_q[i];
        unsafeAtomicAdd(&hsum[(size_t)s*16 + e], y);   // distributed addresses: pipelines fine
    }
}

// ============ P[s][r][e] = sum lat2row[r]*relu(hsum[o]+b1); per-block V0h partials ============
__global__ __launch_bounds__(256) void k_P(const int* __restrict__ offs,
                                           const int* __restrict__ o_at_p,
                                           const float* __restrict__ lat2p,
                                           const float* __restrict__ hsum,
                                           const float* __restrict__ b1,
                                           float* __restrict__ P,
                                           float* __restrict__ pbV){
    int gid = blockIdx.x*256 + threadIdx.x;
    int n = gid >> 4, e = gid & 15;
    float be = b1[e];
    float acc[RP];
    #pragma unroll
    for (int r = 0; r < RP; r++) acc[r] = 0.f;
    if (n < NN){
        int b = offs[n], en = offs[n+1];
        for (int i = b; i < en; i++){
            int o = o_at_p[i];
            float hv = fmaxf(hsum[(size_t)o*16 + e] + be, 0.f);
            const float4* lp = (const float4*)(lat2p + (size_t)i*16);
            float4 v0 = lp[0], v1 = lp[1], v2 = lp[2], v3 = lp[3];
            acc[0] += v0.x*hv; acc[1] += v0.y*hv; acc[2] += v0.z*hv; acc[3] += v0.w*hv;
            acc[4] += v1.x*hv; acc[5] += v1.y*hv; acc[6] += v1.z*hv; acc[7] += v1.w*hv;
            acc[8] += v2.x*hv; acc[9] += v2.y*hv; acc[10]+= v2.z*hv; acc[11]+= v2.w*hv;
            acc[12]+= v3.x*hv; acc[13]+= v3.y*hv; acc[14]+= v3.z*hv; acc[15]+= v3.w*hv;
        }
        float* Pn = P + (size_t)n*240 + e;      // rows r=1..15 only
        #pragma unroll
        for (int r = 1; r < RP; r++) Pn[(r-1)*16] = acc[r];
    }
    // per-block V0h partials (NO same-line atomics)
    __shared__ float sm[256];
    sm[threadIdx.x] = acc[0]; __syncthreads();
    if (threadIdx.x < 16){
        float s = 0.f;
        #pragma unroll
        for (int k = 0; k < 16; k++) s += sm[k*16 + threadIdx.x];
        pbV[(size_t)blockIdx.x*16 + threadIdx.x] = s;
    }
}

// ============ reduce per-block V0h partials -> S0V[2..17] ============
__global__ __launch_bounds__(256) void k_red2(const float* __restrict__ pbV,
                                              float* __restrict__ S0V){
    int e = blockIdx.x;                   // one block per e (16 blocks)
    __shared__ float sm[256];
    int tid = threadIdx.x;
    float a = 0.f;
    for (int i = tid; i < NB16; i += 256) a += pbV[(size_t)i*16 + e];
    sm[tid] = a; __syncthreads();
    for (int off = 128; off > 0; off >>= 1){
        if (tid < off) sm[tid] += sm[tid+off];
        __syncthreads();
    }
    if (tid == 0) S0V[2 + e] = sm[0];
}

// ============ fused h2 + output einsum ============
__global__ __launch_bounds__(256) void k_out(const float* __restrict__ P,
                                             const float* __restrict__ invr,
                                             const float* __restrict__ S0V,
                                             const float* __restrict__ w2,
                                             const float* __restrict__ b2,
                                             float* __restrict__ out){
    int n = blockIdx.x*256 + threadIdx.x;
    if (n >= NN) return;
    float acc[NUMCLS];
    #pragma unroll
    for (int cl = 0; cl < NUMCLS; cl++) acc[cl] = b2[cl];
    #pragma unroll 1
    for (int rr = 0; rr < RP; rr++){
        int c = rr*NN + n;                 // flat h2 row consumed exactly once
        float hrow[EMB];
        #pragma unroll
        for (int e = 0; e < EMB; e++) hrow[e] = 0.f;
        if (c == 0){
            #pragma unroll
            for (int e = 0; e < EMB; e++) hrow[e] = S0V[2 + e];
        }
        #pragma unroll
        for (int r = 1; r < RP; r++){
            int q = c / r;                 // const divisor -> magic mul
            if (q*r == c && q < NN){
                const float* Pr = P + (size_t)q*240 + (r-1)*16;
                #pragma unroll
                for (int e = 0; e < EMB; e++) hrow[e] += Pr[e];
            }
        }
        float inv = invr[c];
        const float* wr = w2 + (size_t)rr*EMB*NUMCLS;   // wave-uniform -> s_load
        #pragma unroll
        for (int e = 0; e < EMB; e++){
            float x = hrow[e] * inv;
            #pragma unroll
            for (int cl = 0; cl < NUMCLS; cl++) acc[cl] += x * wr[e*NUMCLS + cl];
        }
    }
    float4* op = (float4*)(out + (size_t)n*NUMCLS);
    #pragma unroll
    for (int q = 0; q < NUMCLS/4; q++)
        op[q] = make_float4(acc[4*q], acc[4*q+1], acc[4*q+2], acc[4*q+3]);
}

extern "C" void kernel_launch(void* const* d_in, const int* in_sizes, int n_in,
                              void* d_out, int out_size, void* d_ws, size_t ws_size,
                              hipStream_t stream)
{
    const float* nhots = (const float*)d_in[0];
    const float* Wl1   = (const float*)d_in[1];
    const float* bl1   = (const float*)d_in[2];
    const float* Wl2   = (const float*)d_in[3];
    const float* bl2   = (const float*)d_in[4];
    const float* w1    = (const float*)d_in[5];
    const float* w2    = (const float*)d_in[6];
    const float* b1    = (const float*)d_in[7];
    const float* b2    = (const float*)d_in[8];
    const int* srow = (const int*)d_in[9];    // hrow[t] = s[t] for t < NT
    const int* ocol = (const int*)d_in[12];   // vcol[t] = o[t] for t < NT

    // ---- workspace layout (floats) ----
    float* base = (float*)d_ws;
    float* P     = base;                        // 24M floats (NN*240)
    float* lat1q = base;                        // 8M  (dead after k_y)
    float* C     = base + (size_t)8000000;      // 1.6M (dead after k_sums)
    float* Rm    = base + (size_t)9600000;      // 1.6M (dead after k_sums)
    float* lat2p = base + (size_t)24000000;     // 8M  (live k_lat -> k_P)
    float* invc  = base + (size_t)32000000;     // 1.6M
    float* invr  = base + (size_t)33600000;     // 1.6M
    float* hsum  = base + (size_t)35200000;     // 1.6M
    float* S0V   = base + (size_t)36800000;     // 32: [S0c, S0r, V0h[16], pad]
    int*   cnt   = (int*)(base + (size_t)36800032);
    int*   cur   = cnt;                         // cnt dead after scan -> reuse as cur
    int*   offs  = cnt + MM;                    // MM+1
    int*   bsum  = offs + (MM+1);               // SCAN_BLOCKS (pad to 1024)
    int*   btot  = bsum + 1024;
    int*   o_at_p = btot + 1024;                // NT
    int*   s_at_q = o_at_p + NT;                // NT
    float* pbC   = (float*)(s_at_q + NT);       // NB16
    float* pbR   = pbC + NB16;                  // NB16
    float* pbV   = pbR + NB16;                  // NB16*16
    // total ~153.5 MB

    hipMemsetAsync(cnt, 0, (size_t)MM*4, stream);
    hipMemsetAsync(hsum, 0, (size_t)NN*16*4, stream);

    const int EB = (NT + 255)/256;       // 1954
    const int CB = (NRP + 255)/256;      // 6250
    const int NB = (NN + 255)/256;       // 391

    k_count   <<<EB, 256, 0, stream>>>(srow, ocol, cnt);
    k_scan_blk<<<SCAN_BLOCKS, 256, 0, stream>>>(cnt, offs, bsum);
    k_scan_top<<<1, 1024, 0, stream>>>(bsum, btot);
    k_scan_add<<<SCAN_BLOCKS, 256, 0, stream>>>(offs, btot, cur);
    k_lat     <<<EB, 256, 0, stream>>>(nhots, Wl1, bl1, Wl2, bl2, srow, ocol,
                                       cur, lat1q, lat2p, o_at_p, s_at_q);
    k_CR      <<<NB16, 256, 0, stream>>>(offs, lat1q, lat2p, C, Rm, pbC, pbR);
    k_red1    <<<1, 1024, 0, stream>>>(pbC, pbR, S0V);
    k_sums    <<<CB, 256, 0, stream>>>(C, Rm, S0V, invc, invr);
    k_y       <<<NB16, 256, 0, stream>>>(offs, lat1q, s_at_q, invc, w1, hsum);
    k_P       <<<NB16, 256, 0, stream>>>(offs, o_at_p, lat2p, hsum, b1, P, pbV);
    k_red2    <<<16, 256, 0, stream>>>(pbV, S0V);
    k_out     <<<NB, 256, 0, stream>>>(P, invr, S0V, w2, b2, (float*)d_out);
}